// Round 6
// baseline (389.067 us; speedup 1.0000x reference)
//
#include <hip/hip_runtime.h>
#include <math.h>

#define NUM_CODES 128
#define CODE_DIM  64
#define B_ 64
#define D_ 64
#define T_ 8192
#define N_TOK (B_ * T_)   // 524288

// ws layout: c2h[128] | counts[128] | ct[64*128] (centroids transposed)
// ---------------------------------------------------------------------------
// prep: half centroid norms (EXACT round-4 arithmetic), zero histogram,
// transpose centroids -> ct[d][k]
// ---------------------------------------------------------------------------
__global__ __launch_bounds__(128) void kmeans_prep(
    const float* __restrict__ centroids, float* __restrict__ c2h,
    unsigned int* __restrict__ counts, float* __restrict__ ct)
{
    int k = threadIdx.x;   // 0..127
    const float* cp = centroids + k * CODE_DIM;
    float s0 = 0.f, s1 = 0.f, s2 = 0.f, s3 = 0.f;
    #pragma unroll
    for (int d = 0; d < CODE_DIM; d += 4) {
        float c0 = cp[d], c1 = cp[d+1], c2 = cp[d+2], c3 = cp[d+3];
        ct[(d+0)*NUM_CODES + k] = c0;
        ct[(d+1)*NUM_CODES + k] = c1;
        ct[(d+2)*NUM_CODES + k] = c2;
        ct[(d+3)*NUM_CODES + k] = c3;
        s0 = fmaf(c0, c0, s0); s1 = fmaf(c1, c1, s1);
        s2 = fmaf(c2, c2, s2); s3 = fmaf(c3, c3, s3);
    }
    c2h[k] = 0.5f * ((s0 + s1) + (s2 + s3));
    counts[k] = 0u;
}

// ---------------------------------------------------------------------------
// assign: block = 4 waves; lane owns ONE token (n0+lane), wave w owns
// centroids [32w,32w+32). Centroids staged in LDS; per d the wave reads 32
// contiguous floats at a wave-uniform address (broadcast ds_read_b128 -> no
// conflicts, no scalar-cache thrash). z streamed as coalesced dword loads.
// Per-(token,k) arithmetic is BITWISE IDENTICAL to the round-4 kernel that
// passed with absmax 0: chain a0 over even d starting at -0.5||c||^2, chain
// a1 over odd d starting at 0, m = a0+a1; scan i asc then wave asc, strict
// '>' => JAX first-min tie-break.
// ---------------------------------------------------------------------------
__global__ __launch_bounds__(256, 4) void kmeans_assign(
    const float* __restrict__ z_e, const float* __restrict__ ct,
    const float* __restrict__ c2h, unsigned int* __restrict__ counts,
    float* __restrict__ out_idx)
{
    __shared__ float        ctl[CODE_DIM][NUM_CODES];  // 32 KB
    __shared__ float        c2l[NUM_CODES];
    __shared__ float        sb[4][64];
    __shared__ int          si[4][64];
    __shared__ unsigned int hist[NUM_CODES];

    const int tid   = threadIdx.x;
    const int lane  = tid & 63;
    const int w     = tid >> 6;       // 0..3
    const int kbase = w * 32;

    // stage ct (8192 floats = 2048 float4), c2h, zero hist
    {
        const float4* src = (const float4*)ct;
        float4*       dst = (float4*)(&ctl[0][0]);
        #pragma unroll
        for (int r = 0; r < 8; ++r) dst[r * 256 + tid] = src[r * 256 + tid];
        if (tid < NUM_CODES) { c2l[tid] = c2h[tid]; hist[tid] = 0u; }
    }
    __syncthreads();

    const int n0 = blockIdx.x * 64;              // token base
    const int b  = n0 >> 13;                     // / T_
    const int t  = (n0 & (T_ - 1)) + lane;
    const float* zp = z_e + (size_t)b * (size_t)(D_ * T_) + t;

    float acc0[32], acc1[32];
    #pragma unroll
    for (int i = 0; i < 32; ++i) { acc0[i] = -c2l[kbase + i]; acc1[i] = 0.f; }

    #pragma unroll 2
    for (int d = 0; d < CODE_DIM; d += 2) {
        float z0 = zp[(size_t)(d + 0) * T_];
        float z1 = zp[(size_t)(d + 1) * T_];
        const float4* c0 = (const float4*)(&ctl[d + 0][kbase]);  // uniform addr
        const float4* c1 = (const float4*)(&ctl[d + 1][kbase]);  // -> broadcast
        #pragma unroll
        for (int q = 0; q < 8; ++q) {
            float4 ca = c0[q], cb = c1[q];
            acc0[4*q+0] = fmaf(ca.x, z0, acc0[4*q+0]);
            acc0[4*q+1] = fmaf(ca.y, z0, acc0[4*q+1]);
            acc0[4*q+2] = fmaf(ca.z, z0, acc0[4*q+2]);
            acc0[4*q+3] = fmaf(ca.w, z0, acc0[4*q+3]);
            acc1[4*q+0] = fmaf(cb.x, z1, acc1[4*q+0]);
            acc1[4*q+1] = fmaf(cb.y, z1, acc1[4*q+1]);
            acc1[4*q+2] = fmaf(cb.z, z1, acc1[4*q+2]);
            acc1[4*q+3] = fmaf(cb.w, z1, acc1[4*q+3]);
        }
    }

    // per-lane argmax over this wave's 32 centroids (i asc = k asc)
    float bA = -3.4e38f; int iA = kbase;
    #pragma unroll
    for (int i = 0; i < 32; ++i) {
        float m = acc0[i] + acc1[i];               // a0 + a1, as in round 4
        if (m > bA) { bA = m; iA = kbase + i; }
    }
    sb[w][lane] = bA; si[w][lane] = iA;
    __syncthreads();

    // cross-wave reduce (w asc, strict '>' keeps lowest k) by wave 0
    if (w == 0) {
        float bb = sb[0][lane]; int bi = si[0][lane];
        #pragma unroll
        for (int ww = 1; ww < 4; ++ww) {
            float v = sb[ww][lane];
            if (v > bb) { bb = v; bi = si[ww][lane]; }
        }
        out_idx[n0 + lane] = (float)bi;
        atomicAdd(&hist[bi], 1u);
    }
    __syncthreads();
    if (tid < NUM_CODES) {
        unsigned int h = hist[tid];
        if (h) atomicAdd(&counts[tid], h);
    }
}

// ---------------------------------------------------------------------------
// finalize: entropy -> perplexity, usage
// ---------------------------------------------------------------------------
__global__ __launch_bounds__(128) void kmeans_finalize(
    const unsigned int* __restrict__ counts, float* __restrict__ out)
{
    const int k = threadIdx.x;  // 0..127
    unsigned int c = counts[k];
    float p = fmaxf((float)c * (1.0f / (float)N_TOK), 1e-12f);
    float h = -p * logf(p);
    float u = (c > 0u) ? 1.0f : 0.0f;

    __shared__ float sh[NUM_CODES];
    __shared__ float su[NUM_CODES];
    sh[k] = h; su[k] = u;
    __syncthreads();
    for (int s = 64; s > 0; s >>= 1) {
        if (k < s) { sh[k] += sh[k + s]; su[k] += su[k + s]; }
        __syncthreads();
    }
    if (k == 0) {
        out[N_TOK + 0] = expf(sh[0]);            // perplexity
        out[N_TOK + 1] = su[0] * (1.0f / 128.f); // usage
    }
}

// ---------------------------------------------------------------------------
extern "C" void kernel_launch(void* const* d_in, const int* in_sizes, int n_in,
                              void* d_out, int out_size, void* d_ws, size_t ws_size,
                              hipStream_t stream)
{
    const float* z_e       = (const float*)d_in[0];
    const float* centroids = (const float*)d_in[1];
    float* out = (float*)d_out;

    float*        c2h    = (float*)d_ws;
    unsigned int* counts = (unsigned int*)d_ws + NUM_CODES;
    float*        ct     = (float*)d_ws + 2 * NUM_CODES;

    kmeans_prep<<<1, 128, 0, stream>>>(centroids, c2h, counts, ct);
    kmeans_assign<<<N_TOK / 64, 256, 0, stream>>>(z_e, ct, c2h, counts, out);
    kmeans_finalize<<<1, 128, 0, stream>>>(counts, out);
}

// Round 7
// 302.364 us; speedup vs baseline: 1.2868x; 1.2868x over previous
//
#include <hip/hip_runtime.h>
#include <math.h>

#define NUM_CODES 128
#define CODE_DIM  64
#define B_ 64
#define D_ 64
#define T_ 8192
#define N_TOK (B_ * T_)   // 524288

// ws layout: c2h[128] | counts[128]
// ---------------------------------------------------------------------------
// prep: half centroid squared norms + zero histogram (round-4 arithmetic)
// ---------------------------------------------------------------------------
__global__ __launch_bounds__(128) void kmeans_prep(
    const float* __restrict__ centroids, float* __restrict__ c2h,
    unsigned int* __restrict__ counts)
{
    int k = threadIdx.x;   // 0..127
    const float* cp = centroids + k * CODE_DIM;
    float s0 = 0.f, s1 = 0.f, s2 = 0.f, s3 = 0.f;
    #pragma unroll
    for (int d = 0; d < CODE_DIM; d += 4) {
        s0 = fmaf(cp[d + 0], cp[d + 0], s0);
        s1 = fmaf(cp[d + 1], cp[d + 1], s1);
        s2 = fmaf(cp[d + 2], cp[d + 2], s2);
        s3 = fmaf(cp[d + 3], cp[d + 3], s3);
    }
    c2h[k] = 0.5f * ((s0 + s1) + (s2 + s3));
    counts[k] = 0u;
}

// ---------------------------------------------------------------------------
// assign: one thread per token.
//   - z column loaded ONCE into registers/AGPRs (64 coalesced dword loads,
//     issued together up front -> latency paid once, not per k).
//   - centroids staged row-major in LDS (32 KB); per k the wave reads 16
//     float4s at wave-uniform addresses -> broadcast ds_read_b128, zero bank
//     conflicts, no scalar-cache thrash (round 4's stall), no global loads
//     in the hot loop (round 6's stall).
//   - per-(token,k) math BITWISE IDENTICAL to passing rounds 4/6: chain a0
//     over even d starting at -0.5||c||^2, chain a1 over odd d starting at
//     0, m = a0+a1; k ascending, strict '>' => JAX first-min tie-break.
// ---------------------------------------------------------------------------
__global__ __launch_bounds__(256, 4) void kmeans_assign(
    const float* __restrict__ z_e, const float* __restrict__ centroids,
    const float* __restrict__ c2h, unsigned int* __restrict__ counts,
    float* __restrict__ out_idx)
{
    __shared__ float        cl[NUM_CODES * CODE_DIM];  // 32 KB, row-major [k][d]
    __shared__ float        c2l[NUM_CODES];
    __shared__ unsigned int hist[NUM_CODES];

    const int tid = threadIdx.x;

    // stage centroids (2048 float4 / 256 threads = 8 each), c2h, zero hist
    {
        const float4* src = (const float4*)centroids;
        float4*       dst = (float4*)cl;
        #pragma unroll
        for (int r = 0; r < 8; ++r) dst[r * 256 + tid] = src[r * 256 + tid];
        if (tid < NUM_CODES) { c2l[tid] = c2h[tid]; hist[tid] = 0u; }
    }

    // z column for this token: 64 coalesced dword loads, all independent
    const int n = blockIdx.x * 256 + tid;        // token id
    const int b = n >> 13;                       // / T_
    const int t = n & (T_ - 1);
    const float* zp = z_e + (size_t)b * (size_t)(D_ * T_) + t;
    float z[64];
    #pragma unroll
    for (int d = 0; d < 64; ++d) z[d] = zp[(size_t)d * T_];

    __syncthreads();

    float best = -3.4e38f;
    int   bi   = 0;

    #pragma unroll 2
    for (int k = 0; k < NUM_CODES; ++k) {
        const float4* cp4 = (const float4*)(cl + k * CODE_DIM);  // wave-uniform
        float a0 = -c2l[k], a1 = 0.f;
        #pragma unroll
        for (int q = 0; q < 16; ++q) {           // 16 broadcast ds_read_b128
            float4 c = cp4[q];                   // {c[4q],c[4q+1],c[4q+2],c[4q+3]}
            a0 = fmaf(c.x, z[4*q + 0], a0);      // even d -> chain a0
            a1 = fmaf(c.y, z[4*q + 1], a1);      // odd  d -> chain a1
            a0 = fmaf(c.z, z[4*q + 2], a0);
            a1 = fmaf(c.w, z[4*q + 3], a1);
        }
        float m = a0 + a1;                       // z.c - 0.5||c||^2
        if (m > best) { best = m; bi = k; }      // first-max == first-min dist
    }

    out_idx[n] = (float)bi;

    // block histogram -> global atomics
    atomicAdd(&hist[bi], 1u);
    __syncthreads();
    if (tid < NUM_CODES) {
        unsigned int h = hist[tid];
        if (h) atomicAdd(&counts[tid], h);
    }
}

// ---------------------------------------------------------------------------
// finalize: entropy -> perplexity, usage
// ---------------------------------------------------------------------------
__global__ __launch_bounds__(128) void kmeans_finalize(
    const unsigned int* __restrict__ counts, float* __restrict__ out)
{
    const int k = threadIdx.x;  // 0..127
    unsigned int c = counts[k];
    float p = fmaxf((float)c * (1.0f / (float)N_TOK), 1e-12f);
    float h = -p * logf(p);
    float u = (c > 0u) ? 1.0f : 0.0f;

    __shared__ float sh[NUM_CODES];
    __shared__ float su[NUM_CODES];
    sh[k] = h; su[k] = u;
    __syncthreads();
    for (int s = 64; s > 0; s >>= 1) {
        if (k < s) { sh[k] += sh[k + s]; su[k] += su[k + s]; }
        __syncthreads();
    }
    if (k == 0) {
        out[N_TOK + 0] = expf(sh[0]);            // perplexity
        out[N_TOK + 1] = su[0] * (1.0f / 128.f); // usage
    }
}

// ---------------------------------------------------------------------------
extern "C" void kernel_launch(void* const* d_in, const int* in_sizes, int n_in,
                              void* d_out, int out_size, void* d_ws, size_t ws_size,
                              hipStream_t stream)
{
    const float* z_e       = (const float*)d_in[0];
    const float* centroids = (const float*)d_in[1];
    float* out = (float*)d_out;

    float*        c2h    = (float*)d_ws;
    unsigned int* counts = (unsigned int*)d_ws + NUM_CODES;

    kmeans_prep<<<1, 128, 0, stream>>>(centroids, c2h, counts);
    kmeans_assign<<<N_TOK / 256, 256, 0, stream>>>(z_e, centroids, c2h, counts, out);
    kmeans_finalize<<<1, 128, 0, stream>>>(counts, out);
}

// Round 8
// 281.114 us; speedup vs baseline: 1.3840x; 1.0756x over previous
//
#include <hip/hip_runtime.h>
#include <math.h>

#define NUM_CODES 128
#define CODE_DIM  64
#define B_ 64
#define D_ 64
#define T_ 8192
#define N_TOK (B_ * T_)   // 524288

// ws layout: c2h[128] | counts[128]
// ---------------------------------------------------------------------------
// prep: half centroid squared norms + zero histogram (round-4 arithmetic)
// ---------------------------------------------------------------------------
__global__ __launch_bounds__(128) void kmeans_prep(
    const float* __restrict__ centroids, float* __restrict__ c2h,
    unsigned int* __restrict__ counts)
{
    int k = threadIdx.x;   // 0..127
    const float* cp = centroids + k * CODE_DIM;
    float s0 = 0.f, s1 = 0.f, s2 = 0.f, s3 = 0.f;
    #pragma unroll
    for (int d = 0; d < CODE_DIM; d += 4) {
        s0 = fmaf(cp[d + 0], cp[d + 0], s0);
        s1 = fmaf(cp[d + 1], cp[d + 1], s1);
        s2 = fmaf(cp[d + 2], cp[d + 2], s2);
        s3 = fmaf(cp[d + 3], cp[d + 3], s3);
    }
    c2h[k] = 0.5f * ((s0 + s1) + (s2 + s3));
    counts[k] = 0u;
}

// ---------------------------------------------------------------------------
// assign: block = 4 waves, 128 tokens. Lane owns TWO adjacent tokens
// (n0+2*lane, +1) -> float2 z loads (round 4's passing mapping). Wave w owns
// centroids [32w,32w+32) (round 6's passing k-split + reduce). Centroids in
// LDS row-major; per k the wave reads 16 wave-uniform broadcast ds_read_b128
// feeding 128 FMA instrs (1:8 feed ratio; round 7 was 1:4 and stalled at 47%
// VALUBusy). z columns loaded ONCE up front into the unified VGPR/AGPR file.
// Per-(token,k) math BITWISE IDENTICAL to passing rounds 4/6/7: chain a0
// over even d from -0.5||c||^2, chain a1 over odd d from 0, m=a0+a1;
// i asc within wave, w asc across waves, strict '>' => JAX first-min.
// ---------------------------------------------------------------------------
__global__ __launch_bounds__(256, 2) void kmeans_assign(
    const float* __restrict__ z_e, const float* __restrict__ centroids,
    const float* __restrict__ c2h, unsigned int* __restrict__ counts,
    float* __restrict__ out_idx)
{
    __shared__ float        cl[NUM_CODES * CODE_DIM];  // 32 KB row-major [k][d]
    __shared__ float        c2l[NUM_CODES];
    __shared__ float        sb[4][128];
    __shared__ int          si[4][128];
    __shared__ unsigned int hist[NUM_CODES];

    const int tid   = threadIdx.x;
    const int lane  = tid & 63;
    const int w     = tid >> 6;       // 0..3
    const int kbase = w * 32;

    // stage centroids (2048 float4 / 256 threads = 8 each), c2h, zero hist
    {
        const float4* src = (const float4*)centroids;
        float4*       dst = (float4*)cl;
        #pragma unroll
        for (int r = 0; r < 8; ++r) dst[r * 256 + tid] = src[r * 256 + tid];
        if (tid < NUM_CODES) { c2l[tid] = c2h[tid]; hist[tid] = 0u; }
    }

    // z columns for tokens (b,t0),(b,t0+1), loaded once (float2, coalesced)
    const int n0 = blockIdx.x * 128 + 2 * lane;  // first token (even)
    const int b  = n0 >> 13;                     // / T_
    const int t0 = n0 & (T_ - 1);
    const float* zp = z_e + (size_t)b * (size_t)(D_ * T_) + t0;
    float za[64], zb[64];
    #pragma unroll
    for (int d = 0; d < 64; ++d) {
        float2 v = *(const float2*)(zp + (size_t)d * T_);
        za[d] = v.x; zb[d] = v.y;
    }

    __syncthreads();

    // this wave's 32 centroids; per k: 16 broadcast b128 -> 128 FMA instrs
    float bA = -3.4e38f, bB = -3.4e38f;
    int   iA = kbase,    iB = kbase;

    #pragma unroll 2
    for (int i = 0; i < 32; ++i) {
        const int k = kbase + i;
        const float4* cp4 = (const float4*)(cl + k * CODE_DIM);  // uniform
        float nh = -c2l[k];
        float a0 = nh, a1 = 0.f, b0 = nh, b1 = 0.f;
        #pragma unroll
        for (int q = 0; q < 16; ++q) {
            float4 c = cp4[q];                   // d = 4q .. 4q+3
            a0 = fmaf(c.x, za[4*q + 0], a0);
            a1 = fmaf(c.y, za[4*q + 1], a1);
            a0 = fmaf(c.z, za[4*q + 2], a0);
            a1 = fmaf(c.w, za[4*q + 3], a1);
            b0 = fmaf(c.x, zb[4*q + 0], b0);
            b1 = fmaf(c.y, zb[4*q + 1], b1);
            b0 = fmaf(c.z, zb[4*q + 2], b0);
            b1 = fmaf(c.w, zb[4*q + 3], b1);
        }
        float ma = a0 + a1, mb = b0 + b1;        // z.c - 0.5||c||^2
        if (ma > bA) { bA = ma; iA = k; }        // i asc = k asc
        if (mb > bB) { bB = mb; iB = k; }
    }

    sb[w][2*lane]   = bA;  si[w][2*lane]   = iA;
    sb[w][2*lane+1] = bB;  si[w][2*lane+1] = iB;
    __syncthreads();

    // cross-wave reduce (w asc, strict '>' keeps lowest k) by wave 0
    const int nblk = blockIdx.x * 128;
    if (w == 0) {
        #pragma unroll
        for (int r = 0; r < 2; ++r) {
            int tok = lane + 64 * r;             // coalesced stores
            float bb = sb[0][tok]; int bi = si[0][tok];
            #pragma unroll
            for (int ww = 1; ww < 4; ++ww) {
                float v = sb[ww][tok];
                if (v > bb) { bb = v; bi = si[ww][tok]; }
            }
            out_idx[nblk + tok] = (float)bi;
            atomicAdd(&hist[bi], 1u);
        }
    }
    __syncthreads();
    if (tid < NUM_CODES) {
        unsigned int h = hist[tid];
        if (h) atomicAdd(&counts[tid], h);
    }
}

// ---------------------------------------------------------------------------
// finalize: entropy -> perplexity, usage
// ---------------------------------------------------------------------------
__global__ __launch_bounds__(128) void kmeans_finalize(
    const unsigned int* __restrict__ counts, float* __restrict__ out)
{
    const int k = threadIdx.x;  // 0..127
    unsigned int c = counts[k];
    float p = fmaxf((float)c * (1.0f / (float)N_TOK), 1e-12f);
    float h = -p * logf(p);
    float u = (c > 0u) ? 1.0f : 0.0f;

    __shared__ float sh[NUM_CODES];
    __shared__ float su[NUM_CODES];
    sh[k] = h; su[k] = u;
    __syncthreads();
    for (int s = 64; s > 0; s >>= 1) {
        if (k < s) { sh[k] += sh[k + s]; su[k] += su[k + s]; }
        __syncthreads();
    }
    if (k == 0) {
        out[N_TOK + 0] = expf(sh[0]);            // perplexity
        out[N_TOK + 1] = su[0] * (1.0f / 128.f); // usage
    }
}

// ---------------------------------------------------------------------------
extern "C" void kernel_launch(void* const* d_in, const int* in_sizes, int n_in,
                              void* d_out, int out_size, void* d_ws, size_t ws_size,
                              hipStream_t stream)
{
    const float* z_e       = (const float*)d_in[0];
    const float* centroids = (const float*)d_in[1];
    float* out = (float*)d_out;

    float*        c2h    = (float*)d_ws;
    unsigned int* counts = (unsigned int*)d_ws + NUM_CODES;

    kmeans_prep<<<1, 128, 0, stream>>>(centroids, c2h, counts);
    kmeans_assign<<<N_TOK / 128, 256, 0, stream>>>(z_e, centroids, c2h, counts, out);
    kmeans_finalize<<<1, 128, 0, stream>>>(counts, out);
}